// Round 23
// baseline (81.973 us; speedup 1.0000x reference)
//
#include <hip/hip_runtime.h>
#include <hip/hip_bf16.h>
#include <hip/hip_fp8.h>
#include <stdint.h>

// TripletLoss (n=4096, d=2048, K=4) — fused fp8-MFMA distance + mining.
//   1. prep: fp32 -> fp8 e4m3 via HW v_cvt_pk_fp8_f32; 64B-row-tile permuted
//      layout: pos(k) = (k>>6)*64 + ((k>>3)&3)*16 + ((k>>5)&1)*8. Common
//      k-perm of A@A^T is invariant. sq[] fp32-exact; neg_min + work_ctr init.
//   2. gemm: R20's proven best config (128x128 tile, 4 waves x 64x64, BK=64,
//      8-phase 2-barrier skeleton, VMW(2) at ph4/ph8, aligned-quad 64B-row
//      swizzle = 0 conflicts, 0.25 ds_read/MFMA) wrapped in PERSISTENT
//      WORK-STEALING: 512 blocks (2/CU, fully co-resident) grab tile ids via
//      atomicAdd until 528 tiles done. Kills R20's 3-vs-2 blocks/CU makespan
//      tail (~1.45x stretch). R22 lesson: occupancy via thinner waves loses
//      to read-ratio; balance instead. Output order-independent (atomicMin,
//      disjoint dist_ap). Fused epilogue: dist, row/col mins, diag dist_ap.
//   3. finalize: separate 1-block kernel (R14: device-fence fusion costs 86us).

#define N_ROWS 4096
#define DIM    2048
#define P_IDS  1024
#define NPAIR  (P_IDS * 6)
#define MARGIN 0.3f
#define BK     64           // fp8 k (= bytes) per K-tile row
#define NT     (DIM / BK)   // 32 K-tiles
#define NIT    (NT / 2)     // 16 iterations (2 K-tiles each)
#define NTILE  32           // 4096 / 128
#define NBLK   528          // 32*33/2 triangular tiles (work items)
#define NPERS  512          // persistent blocks (2 per CU)

typedef __attribute__((ext_vector_type(4))) float f32x4;
typedef __attribute__((ext_vector_type(2))) long long2v;

__global__ __launch_bounds__(256) void prep_kernel(const float* __restrict__ in,
                                                   uint8_t* __restrict__ f8m,
                                                   float* __restrict__ sq,
                                                   unsigned* __restrict__ neg_bits,
                                                   unsigned* __restrict__ work_ctr) {
    const int row = blockIdx.x;
    const int t = threadIdx.x;
    const float4* rp = (const float4*)(in + (size_t)row * DIM);
    float4 v0 = rp[t * 2 + 0];
    float4 v1 = rp[t * 2 + 1];
    float s = v0.x * v0.x + v0.y * v0.y + v0.z * v0.z + v0.w * v0.w
            + v1.x * v1.x + v1.y * v1.y + v1.z * v1.z + v1.w * v1.w;
    unsigned w0 = (unsigned)__builtin_amdgcn_cvt_pk_fp8_f32(v0.x, v0.y, 0, false);
    w0 = (unsigned)__builtin_amdgcn_cvt_pk_fp8_f32(v0.z, v0.w, (int)w0, true);
    unsigned w1 = (unsigned)__builtin_amdgcn_cvt_pk_fp8_f32(v1.x, v1.y, 0, false);
    w1 = (unsigned)__builtin_amdgcn_cvt_pk_fp8_f32(v1.z, v1.w, (int)w1, true);
    // 64B-row-tile layout: thread t holds k = 8t..8t+7 (ktile = t>>3,
    // granule = t&3, half = (t>>2)&1) -> pos = (t>>3)*64 + (t&3)*16
    // + ((t>>2)&1)*8.
    const int pos = (t >> 3) * 64 + (t & 3) * 16 + ((t >> 2) & 1) * 8;
    uint2 o; o.x = w0; o.y = w1;
    *(uint2*)(f8m + (size_t)row * DIM + pos) = o;
    #pragma unroll
    for (int m = 32; m; m >>= 1) s += __shfl_down(s, m, 64);
    __shared__ float red[4];
    if ((t & 63) == 0) red[t >> 6] = s;
    __syncthreads();
    if (t == 0) {
        sq[row] = red[0] + red[1] + red[2] + red[3];
        neg_bits[row] = 0x7F800000u;  // +inf
        if (row == 0) work_ctr[0] = 0;
    }
}

__global__ __launch_bounds__(256, 4) void gemm_kernel(const uint8_t* __restrict__ f8m,
                                                      const float* __restrict__ sq,
                                                      unsigned* __restrict__ neg_bits,
                                                      float* __restrict__ dist_ap,
                                                      unsigned* __restrict__ work_ctr) {
    extern __shared__ char smem[];              // 32 KiB dynamic LDS + 4B tile id
    uint8_t* const Asb = (uint8_t*)smem;        // [2][128][64] B (16 KiB)
    uint8_t* const Bsb = (uint8_t*)(smem + 16384);
    int* const s_tile = (int*)(smem + 32768);
    #define AS(B,R,C) Asb[((B) << 13) + ((R) << 6) + (C)]
    #define BS(B,R,C) Bsb[((B) << 13) + ((R) << 6) + (C)]

    const int t = threadIdx.x;
    const int lane = t & 63;
    const int wave = t >> 6;             // 0..3
    const int wr = (wave >> 1) * 64;     // M-half (2 waves)
    const int wc = (wave & 1) * 64;      // N-half (2 waves)
    const int lr = lane & 15;
    const int l4 = lane >> 4;            // 0..3 = fragment k-quarter
    const int sr  = lane >> 2;                       // 0..15 row in chunk
    const int gg  = (lane & 3) ^ ((lane >> 3) & 3);  // source granule
    const int l15 = lane & 15;

    #define VMW(N) asm volatile("s_waitcnt vmcnt(" #N ")" ::: "memory")
    #define BARR() __builtin_amdgcn_s_barrier()

    while (true) {
        // ---- grab next tile (work-stealing) ----
        if (t == 0) s_tile[0] = (int)atomicAdd(work_ctr, 1u);
        __syncthreads();
        const int tile = s_tile[0];
        __syncthreads();   // all read s_tile before next overwrite
        if (tile >= NBLK) return;   // block-uniform exit
        int rem = tile, bi = 0;
        while (rem >= NTILE - bi) { rem -= NTILE - bi; ++bi; }
        const int bj = bi + rem;   // bi <= bj

        f32x4 acc[4][4] = {};
        const int rowA0 = bi * 128;
        const int rowB0 = bj * 128;
        const uint8_t* gA = f8m + (size_t)(rowA0 + sr) * DIM + (gg << 4);
        const uint8_t* gB = f8m + (size_t)(rowB0 + sr) * DIM + (gg << 4);

        // Stage one full 128-row K-tile (8 KiB, 8 chunks): 2 gloads/wave.
        #define STAGE_HT(GBASE, LDSB, BUF, KT)                                    \
            { _Pragma("unroll")                                                   \
              for (int g = 0; g < 2; ++g) {                                       \
                  const int chunk = wave * 2 + g;                                 \
                  __builtin_amdgcn_global_load_lds(                               \
                      (const __attribute__((address_space(1))) void*)             \
                          ((GBASE) + (size_t)chunk * 16 * DIM + (KT) * BK),       \
                      (__attribute__((address_space(3))) void*)                   \
                          ((char*)(LDSB) + (BUF) * 8192 + chunk * 1024),          \
                      16, 0, 0);                                                  \
              } }
        #define STAGE_A(BUF, KT) STAGE_HT(gA, Asb, BUF, KT)
        #define STAGE_B(BUF, KT) STAGE_HT(gB, Bsb, BUF, KT)

        long2v afp[2], bfp0[2], bfp1[2];
        #define SLOTCOL ((l4 ^ ((lr >> 1) & 3)) << 4)
        #define LOAD_AF(BUF, MH)                                                  \
            { _Pragma("unroll") for (int m = 0; m < 2; ++m)                       \
                  afp[m] = *(const long2v*)&AS(BUF,                               \
                      wr + ((MH) * 2 + m) * 16 + lr, SLOTCOL); }
        #define LOAD_BF(DST, BUF, NH)                                             \
            { _Pragma("unroll") for (int n = 0; n < 2; ++n)                       \
                  DST[n] = *(const long2v*)&BS(BUF,                               \
                      wc + ((NH) * 2 + n) * 16 + lr, SLOTCOL); }

        #define MFMA_Q(MH, NH, BF)                                                \
            { __builtin_amdgcn_s_setprio(1);                                      \
              _Pragma("unroll") for (int ks = 0; ks < 2; ++ks)                    \
              _Pragma("unroll") for (int m = 0; m < 2; ++m)                       \
              _Pragma("unroll") for (int n = 0; n < 2; ++n)                       \
                  acc[(MH) * 2 + m][(NH) * 2 + n] =                               \
                      __builtin_amdgcn_mfma_f32_16x16x32_fp8_fp8(                 \
                          afp[m][ks], BF[n][ks],                                  \
                          acc[(MH) * 2 + m][(NH) * 2 + n], 0, 0, 0);              \
              __builtin_amdgcn_s_setprio(0); }

        // Prologue: A(0), B(0) -> buf0; B(1) -> buf1. (A(1) staged in ph1.)
        STAGE_A(0, 0);
        STAGE_B(0, 0);
        STAGE_B(1, 1);
        VMW(0);
        BARR();

        // Ledger (gloads/wave): entering iter B(t+1)=2. ph1 +A(t+1)=4;
        // ph3 +B(t+2)=6; ph4 VMW(2) drains B(t+1),A(t+1); ph5 +A(t+2)=4;
        // ph7 +B(t+3)=6; ph8 VMW(2) drains B(t+2),A(t+2).
        for (int i = 0; i < NIT - 1; ++i) {
            const int t2 = 2 * i;
            LOAD_AF(0, 0); LOAD_BF(bfp0, 0, 0);
            STAGE_A(1, t2 + 1);
            BARR(); MFMA_Q(0, 0, bfp0); BARR();
            LOAD_BF(bfp1, 0, 1);
            BARR(); MFMA_Q(0, 1, bfp1); BARR();
            LOAD_AF(0, 1);
            STAGE_B(0, t2 + 2);
            BARR(); MFMA_Q(1, 1, bfp1); BARR();
            BARR(); MFMA_Q(1, 0, bfp0); VMW(2); BARR();
            LOAD_AF(1, 0); LOAD_BF(bfp0, 1, 0);
            STAGE_A(0, t2 + 2);
            BARR(); MFMA_Q(0, 0, bfp0); BARR();
            LOAD_BF(bfp1, 1, 1);
            BARR(); MFMA_Q(0, 1, bfp1); BARR();
            LOAD_AF(1, 1);
            STAGE_B(1, t2 + 3);
            BARR(); MFMA_Q(1, 1, bfp1); BARR();
            BARR(); MFMA_Q(1, 0, bfp0); VMW(2); BARR();
        }
        // Peeled last iteration (t2 = 30): no stages for tiles 32/33.
        {
            LOAD_AF(0, 0); LOAD_BF(bfp0, 0, 0);
            STAGE_A(1, NT - 1);
            BARR(); MFMA_Q(0, 0, bfp0); BARR();
            LOAD_BF(bfp1, 0, 1);
            BARR(); MFMA_Q(0, 1, bfp1); BARR();
            LOAD_AF(0, 1);
            BARR(); MFMA_Q(1, 1, bfp1); BARR();
            BARR(); MFMA_Q(1, 0, bfp0); VMW(0); BARR();
            LOAD_AF(1, 0); LOAD_BF(bfp0, 1, 0);
            BARR(); MFMA_Q(0, 0, bfp0); BARR();
            LOAD_BF(bfp1, 1, 1);
            BARR(); MFMA_Q(0, 1, bfp1); BARR();
            LOAD_AF(1, 1);
            BARR(); MFMA_Q(1, 1, bfp1); BARR();
            MFMA_Q(1, 0, bfp0);
            // After the final BARR above, no wave issues further LDS reads,
            // so next-tile staging by early waves cannot race.
        }

        // ---- fused epilogue (16x16 C/D: col=lane&15, row=l4*4+r) ----
        const bool diag = (bi == bj);
        float sqc[4];
        #pragma unroll
        for (int n = 0; n < 4; ++n) sqc[n] = sq[rowB0 + wc + n * 16 + l15];
        float colmin[4] = {INFINITY, INFINITY, INFINITY, INFINITY};

        #pragma unroll
        for (int m = 0; m < 4; ++m) {
            #pragma unroll
            for (int r = 0; r < 4; ++r) {
                const int grow = rowA0 + wr + m * 16 + l4 * 4 + r;
                const float sqr = sq[grow];
                float rmin = INFINITY;
                #pragma unroll
                for (int n = 0; n < 4; ++n) {
                    const int gcol = rowB0 + wc + n * 16 + l15;
                    const float d2 = sqr + sqc[n] - 2.0f * acc[m][n][r];
                    const float d = sqrtf(fmaxf(d2, 1e-12f));
                    float cand = d;
                    if (diag && ((grow >> 2) == (gcol >> 2))) {
                        if (grow < gcol) {  // within-identity pair (a<b)
                            const int p = grow >> 2;
                            const int a = grow & 3, b = gcol & 3;
                            dist_ap[p * 6 + (a * (7 - a)) / 2 + (b - a - 1)] = d;
                        }
                        cand = INFINITY;  // mask positives from mining
                    }
                    rmin = fminf(rmin, cand);
                    colmin[n] = fminf(colmin[n], cand);
                }
                rmin = fminf(rmin, __shfl_xor(rmin, 1, 64));
                rmin = fminf(rmin, __shfl_xor(rmin, 2, 64));
                rmin = fminf(rmin, __shfl_xor(rmin, 4, 64));
                rmin = fminf(rmin, __shfl_xor(rmin, 8, 64));
                if (l15 == 0) atomicMin(&neg_bits[grow], __float_as_uint(rmin));
            }
        }
        if (!diag) {  // transpose contribution (col mins)
            #pragma unroll
            for (int n = 0; n < 4; ++n) {
                float v = colmin[n];
                v = fminf(v, __shfl_xor(v, 16, 64));
                v = fminf(v, __shfl_xor(v, 32, 64));
                if (l4 == 0)
                    atomicMin(&neg_bits[rowB0 + wc + n * 16 + l15],
                              __float_as_uint(v));
            }
        }
    }
}

__global__ __launch_bounds__(256) void finalize_kernel(const unsigned* __restrict__ neg_bits,
                                                       const float* __restrict__ dist_ap,
                                                       float* __restrict__ out) {
    const int t = threadIdx.x;
    float sum = 0.f, cnt = 0.f;
    for (int e = t; e < NPAIR; e += 256) {
        const int p = e / 6;
        const int idx = e - p * 6;
        const int a = (idx < 3) ? 0 : ((idx < 5) ? 1 : 2);  // triu jj for K=4
        const float an = __uint_as_float(neg_bits[p * 4 + a]);
        const float ap = dist_ap[e];
        sum += fmaxf(ap - an + MARGIN, 0.f);
        cnt += (an > ap) ? 1.f : 0.f;
    }
    #pragma unroll
    for (int m = 32; m; m >>= 1) {
        sum += __shfl_down(sum, m, 64);
        cnt += __shfl_down(cnt, m, 64);
    }
    __shared__ float rs[4], rc[4];
    if ((t & 63) == 0) { rs[t >> 6] = sum; rc[t >> 6] = cnt; }
    __syncthreads();
    if (t == 0) {
        out[0] = (rs[0] + rs[1] + rs[2] + rs[3]) / (float)NPAIR;
        out[1] = (rc[0] + rc[1] + rc[2] + rc[3]) / (float)NPAIR;
    }
}

extern "C" void kernel_launch(void* const* d_in, const int* in_sizes, int n_in,
                              void* d_out, int out_size, void* d_ws, size_t ws_size,
                              hipStream_t stream) {
    const float* inputs = (const float*)d_in[0];
    float* out = (float*)d_out;
    char* ws = (char*)d_ws;
    uint8_t* f8m = (uint8_t*)ws;                               // 8 MiB
    float* sq = (float*)(ws + (size_t)N_ROWS * DIM);           // 16 KiB
    unsigned* neg_bits = (unsigned*)((char*)sq + N_ROWS * 4);  // 16 KiB
    float* dist_ap = (float*)((char*)neg_bits + N_ROWS * 4);   // 24 KiB
    unsigned* work_ctr = (unsigned*)((char*)dist_ap + NPAIR * 4);

    prep_kernel<<<N_ROWS, 256, 0, stream>>>(inputs, f8m, sq, neg_bits, work_ctr);
    gemm_kernel<<<NPERS, 256, 32772, stream>>>(f8m, sq, neg_bits, dist_ap,
                                               work_ctr);
    finalize_kernel<<<1, 256, 0, stream>>>(neg_bits, dist_ap, out);
}

// Round 24
// 62.950 us; speedup vs baseline: 1.3022x; 1.3022x over previous
//
#include <hip/hip_runtime.h>
#include <hip/hip_bf16.h>
#include <hip/hip_fp8.h>
#include <stdint.h>

// TripletLoss (n=4096, d=2048, K=4) — fused fp8-MFMA distance + mining.
// R20 configuration restored verbatim (proven best: 45.6us gemm / 64.8us
// total). R21 (1-wave blocks), R22 (2-wave blocks), R23 (persistent
// work-stealing) all regressed — this design point is the validated optimum.
//   1. prep: fp32 -> fp8 e4m3 via HW v_cvt_pk_fp8_f32; 64B-row-tile permuted
//      layout: pos(k) = (k>>6)*64 + ((k>>3)&3)*16 + ((k>>5)&1)*8. Common
//      k-perm of A@A^T is invariant. sq[] fp32-exact; neg_min init.
//   2. gemm: 128x128 tiles, 528 blocks, 256 thr (4 waves x 64x64), BK=64:
//      LDS 32 KiB/block -> 4 co-resident blocks/CU capacity. Proven 8-phase
//      skeleton (2 barriers/phase), ledger: 2-gload stages, VMW(2) at
//      ph4/ph8. 64B-row swizzle (0 conflicts): stage involution
//      gg=(s&3)^((s>>3)&3), read slot = l4^((lr>>1)&3). MFMA
//      16x16x32_fp8_fp8, s_setprio, bijective XCD swizzle (528=8x66).
//      Fused epilogue: dist = sqrt(max(sq_i+sq_j-2*dot,1e-12)); row/col
//      mins -> atomicMin; diagonal tiles emit within-identity dist_ap.
//   3. finalize: separate 1-block kernel (R14: device-fence fusion costs 86us).

#define N_ROWS 4096
#define DIM    2048
#define P_IDS  1024
#define NPAIR  (P_IDS * 6)
#define MARGIN 0.3f
#define BK     64           // fp8 k (= bytes) per K-tile row
#define NT     (DIM / BK)   // 32 K-tiles
#define NIT    (NT / 2)     // 16 iterations (2 K-tiles each)
#define NTILE  32           // 4096 / 128
#define NBLK   528          // 32*33/2 = 8 * 66

typedef __attribute__((ext_vector_type(4))) float f32x4;
typedef __attribute__((ext_vector_type(2))) long long2v;

__global__ __launch_bounds__(256) void prep_kernel(const float* __restrict__ in,
                                                   uint8_t* __restrict__ f8m,
                                                   float* __restrict__ sq,
                                                   unsigned* __restrict__ neg_bits) {
    const int row = blockIdx.x;
    const int t = threadIdx.x;
    const float4* rp = (const float4*)(in + (size_t)row * DIM);
    float4 v0 = rp[t * 2 + 0];
    float4 v1 = rp[t * 2 + 1];
    float s = v0.x * v0.x + v0.y * v0.y + v0.z * v0.z + v0.w * v0.w
            + v1.x * v1.x + v1.y * v1.y + v1.z * v1.z + v1.w * v1.w;
    unsigned w0 = (unsigned)__builtin_amdgcn_cvt_pk_fp8_f32(v0.x, v0.y, 0, false);
    w0 = (unsigned)__builtin_amdgcn_cvt_pk_fp8_f32(v0.z, v0.w, (int)w0, true);
    unsigned w1 = (unsigned)__builtin_amdgcn_cvt_pk_fp8_f32(v1.x, v1.y, 0, false);
    w1 = (unsigned)__builtin_amdgcn_cvt_pk_fp8_f32(v1.z, v1.w, (int)w1, true);
    // 64B-row-tile layout: thread t holds k = 8t..8t+7 (ktile = t>>3,
    // granule = t&3, half = (t>>2)&1) -> pos = (t>>3)*64 + (t&3)*16
    // + ((t>>2)&1)*8.
    const int pos = (t >> 3) * 64 + (t & 3) * 16 + ((t >> 2) & 1) * 8;
    uint2 o; o.x = w0; o.y = w1;
    *(uint2*)(f8m + (size_t)row * DIM + pos) = o;
    #pragma unroll
    for (int m = 32; m; m >>= 1) s += __shfl_down(s, m, 64);
    __shared__ float red[4];
    if ((t & 63) == 0) red[t >> 6] = s;
    __syncthreads();
    if (t == 0) {
        sq[row] = red[0] + red[1] + red[2] + red[3];
        neg_bits[row] = 0x7F800000u;  // +inf
    }
}

__global__ __launch_bounds__(256, 4) void gemm_kernel(const uint8_t* __restrict__ f8m,
                                                      const float* __restrict__ sq,
                                                      unsigned* __restrict__ neg_bits,
                                                      float* __restrict__ dist_ap) {
    extern __shared__ char smem[];              // 32 KiB dynamic LDS
    uint8_t* const Asb = (uint8_t*)smem;        // [2][128][64] B (16 KiB)
    uint8_t* const Bsb = (uint8_t*)(smem + 16384);
    #define AS(B,R,C) Asb[((B) << 13) + ((R) << 6) + (C)]
    #define BS(B,R,C) Bsb[((B) << 13) + ((R) << 6) + (C)]

    // Bijective XCD-chunk swizzle (528 = 8 * 66).
    const int bid = (blockIdx.x & 7) * (NBLK / 8) + (blockIdx.x >> 3);
    int rem = bid, bi = 0;
    while (rem >= NTILE - bi) { rem -= NTILE - bi; ++bi; }
    const int bj = bi + rem;   // bi <= bj

    const int t = threadIdx.x;
    const int lane = t & 63;
    const int wave = t >> 6;             // 0..3
    const int wr = (wave >> 1) * 64;     // M-half (2 waves)
    const int wc = (wave & 1) * 64;      // N-half (2 waves)
    const int lr = lane & 15;
    const int l4 = lane >> 4;            // 0..3 = fragment k-quarter
    f32x4 acc[4][4] = {};

    const int rowA0 = bi * 128;
    const int rowB0 = bj * 128;
    // Staging: chunk = 16 rows x 64B = 1KB. Stage-lane s -> LDS offset s*16
    // (row s>>2, slot s&3); stored granule gg = (s&3)^((s>>3)&3) (involution
    // with the read-side XOR mask (row>>1)&3).
    const int sr  = lane >> 2;                       // 0..15 row in chunk
    const int gg  = (lane & 3) ^ ((lane >> 3) & 3);  // source granule
    const uint8_t* gA = f8m + (size_t)(rowA0 + sr) * DIM + (gg << 4);
    const uint8_t* gB = f8m + (size_t)(rowB0 + sr) * DIM + (gg << 4);

    // Stage one full 128-row K-tile (8 KiB, 8 chunks): 2 gloads/wave.
    #define STAGE_HT(GBASE, LDSB, BUF, KT)                                        \
        { _Pragma("unroll")                                                       \
          for (int g = 0; g < 2; ++g) {                                           \
              const int chunk = wave * 2 + g;                                     \
              __builtin_amdgcn_global_load_lds(                                   \
                  (const __attribute__((address_space(1))) void*)                 \
                      ((GBASE) + (size_t)chunk * 16 * DIM + (KT) * BK),           \
                  (__attribute__((address_space(3))) void*)                       \
                      ((char*)(LDSB) + (BUF) * 8192 + chunk * 1024),              \
                  16, 0, 0);                                                      \
          } }
    #define STAGE_A(BUF, KT) STAGE_HT(gA, Asb, BUF, KT)
    #define STAGE_B(BUF, KT) STAGE_HT(gB, Bsb, BUF, KT)

    // Fragment read: ONE ds_read_b128 per fragment per K-tile (halves =
    // MFMA steps ks=0,1; static component index). Slot = l4 ^ ((lr>>1)&3):
    // per-16-lane group covers 8 bank-quads x 2 lanes = conflict-free.
    long2v afp[2], bfp0[2], bfp1[2];
    #define SLOTCOL ((l4 ^ ((lr >> 1) & 3)) << 4)
    #define LOAD_AF(BUF, MH)                                                      \
        { _Pragma("unroll") for (int m = 0; m < 2; ++m)                           \
              afp[m] = *(const long2v*)&AS(BUF,                                   \
                  wr + ((MH) * 2 + m) * 16 + lr, SLOTCOL); }
    #define LOAD_BF(DST, BUF, NH)                                                 \
        { _Pragma("unroll") for (int n = 0; n < 2; ++n)                           \
              DST[n] = *(const long2v*)&BS(BUF, wc + ((NH) * 2 + n) * 16 + lr,    \
                                           SLOTCOL); }

    // 8 MFMA per quadrant burst (2m x 2n x 2ks); ks outer -> reuse dist 4.
    #define MFMA_Q(MH, NH, BF)                                                    \
        { __builtin_amdgcn_s_setprio(1);                                          \
          _Pragma("unroll") for (int ks = 0; ks < 2; ++ks)                        \
          _Pragma("unroll") for (int m = 0; m < 2; ++m)                           \
          _Pragma("unroll") for (int n = 0; n < 2; ++n)                           \
              acc[(MH) * 2 + m][(NH) * 2 + n] =                                   \
                  __builtin_amdgcn_mfma_f32_16x16x32_fp8_fp8(                     \
                      afp[m][ks], BF[n][ks],                                      \
                      acc[(MH) * 2 + m][(NH) * 2 + n], 0, 0, 0);                  \
          __builtin_amdgcn_s_setprio(0); }

    #define BARR() __builtin_amdgcn_s_barrier()
    #define VMW(N) asm volatile("s_waitcnt vmcnt(" #N ")" ::: "memory")

    // Prologue: A(0), B(0) -> buf0; B(1) -> buf1. (A(1) staged in ph1.)
    STAGE_A(0, 0);
    STAGE_B(0, 0);
    STAGE_B(1, 1);
    VMW(0);
    BARR();

    // Ledger (steady, gloads/wave): entering iter B(t+1)=2 out.
    // ph1 +A(t+1)=4; ph3 +B(t+2)=6; ph4 VMW(2) drains B(t+1),A(t+1);
    // ph5 +A(t+2)=4; ph7 +B(t+3)=6; ph8 VMW(2) drains B(t+2),A(t+2).
    for (int i = 0; i < NIT - 1; ++i) {
        const int t2 = 2 * i;
        // ph1
        LOAD_AF(0, 0); LOAD_BF(bfp0, 0, 0);
        STAGE_A(1, t2 + 1);
        BARR(); MFMA_Q(0, 0, bfp0); BARR();
        // ph2
        LOAD_BF(bfp1, 0, 1);
        BARR(); MFMA_Q(0, 1, bfp1); BARR();
        // ph3
        LOAD_AF(0, 1);
        STAGE_B(0, t2 + 2);
        BARR(); MFMA_Q(1, 1, bfp1); BARR();
        // ph4
        BARR(); MFMA_Q(1, 0, bfp0); VMW(2); BARR();
        // ph5
        LOAD_AF(1, 0); LOAD_BF(bfp0, 1, 0);
        STAGE_A(0, t2 + 2);
        BARR(); MFMA_Q(0, 0, bfp0); BARR();
        // ph6
        LOAD_BF(bfp1, 1, 1);
        BARR(); MFMA_Q(0, 1, bfp1); BARR();
        // ph7
        LOAD_AF(1, 1);
        STAGE_B(1, t2 + 3);
        BARR(); MFMA_Q(1, 1, bfp1); BARR();
        // ph8
        BARR(); MFMA_Q(1, 0, bfp0); VMW(2); BARR();
    }
    // Peeled last iteration (t2 = 30): no stages for tiles 32/33.
    {
        LOAD_AF(0, 0); LOAD_BF(bfp0, 0, 0);
        STAGE_A(1, NT - 1);
        BARR(); MFMA_Q(0, 0, bfp0); BARR();
        LOAD_BF(bfp1, 0, 1);
        BARR(); MFMA_Q(0, 1, bfp1); BARR();
        LOAD_AF(0, 1);
        BARR(); MFMA_Q(1, 1, bfp1); BARR();
        BARR(); MFMA_Q(1, 0, bfp0); VMW(0); BARR();
        LOAD_AF(1, 0); LOAD_BF(bfp0, 1, 0);
        BARR(); MFMA_Q(0, 0, bfp0); BARR();
        LOAD_BF(bfp1, 1, 1);
        BARR(); MFMA_Q(0, 1, bfp1); BARR();
        LOAD_AF(1, 1);
        BARR(); MFMA_Q(1, 1, bfp1); BARR();
        MFMA_Q(1, 0, bfp0);
    }

    // ---- fused epilogue (16x16 C/D layout: col=lane&15, row=l4*4+r) ----
    const bool diag = (bi == bj);
    const int l15 = lane & 15;
    float sqc[4];
    #pragma unroll
    for (int n = 0; n < 4; ++n) sqc[n] = sq[rowB0 + wc + n * 16 + l15];
    float colmin[4] = {INFINITY, INFINITY, INFINITY, INFINITY};

    #pragma unroll
    for (int m = 0; m < 4; ++m) {
        #pragma unroll
        for (int r = 0; r < 4; ++r) {
            const int grow = rowA0 + wr + m * 16 + l4 * 4 + r;
            const float sqr = sq[grow];
            float rmin = INFINITY;
            #pragma unroll
            for (int n = 0; n < 4; ++n) {
                const int gcol = rowB0 + wc + n * 16 + l15;
                const float d2 = sqr + sqc[n] - 2.0f * acc[m][n][r];
                const float d = sqrtf(fmaxf(d2, 1e-12f));
                float cand = d;
                if (diag && ((grow >> 2) == (gcol >> 2))) {
                    if (grow < gcol) {  // within-identity pair (a<b)
                        const int p = grow >> 2;
                        const int a = grow & 3, b = gcol & 3;
                        dist_ap[p * 6 + (a * (7 - a)) / 2 + (b - a - 1)] = d;
                    }
                    cand = INFINITY;  // mask positives from mining
                }
                rmin = fminf(rmin, cand);
                colmin[n] = fminf(colmin[n], cand);
            }
            rmin = fminf(rmin, __shfl_xor(rmin, 1, 64));
            rmin = fminf(rmin, __shfl_xor(rmin, 2, 64));
            rmin = fminf(rmin, __shfl_xor(rmin, 4, 64));
            rmin = fminf(rmin, __shfl_xor(rmin, 8, 64));
            if (l15 == 0) atomicMin(&neg_bits[grow], __float_as_uint(rmin));
        }
    }
    if (!diag) {  // transpose contribution (col mins over the wave's 64 rows)
        #pragma unroll
        for (int n = 0; n < 4; ++n) {
            float v = colmin[n];
            v = fminf(v, __shfl_xor(v, 16, 64));
            v = fminf(v, __shfl_xor(v, 32, 64));
            if (l4 == 0)
                atomicMin(&neg_bits[rowB0 + wc + n * 16 + l15], __float_as_uint(v));
        }
    }
}

__global__ __launch_bounds__(256) void finalize_kernel(const unsigned* __restrict__ neg_bits,
                                                       const float* __restrict__ dist_ap,
                                                       float* __restrict__ out) {
    const int t = threadIdx.x;
    float sum = 0.f, cnt = 0.f;
    for (int e = t; e < NPAIR; e += 256) {
        const int p = e / 6;
        const int idx = e - p * 6;
        const int a = (idx < 3) ? 0 : ((idx < 5) ? 1 : 2);  // triu jj for K=4
        const float an = __uint_as_float(neg_bits[p * 4 + a]);
        const float ap = dist_ap[e];
        sum += fmaxf(ap - an + MARGIN, 0.f);
        cnt += (an > ap) ? 1.f : 0.f;
    }
    #pragma unroll
    for (int m = 32; m; m >>= 1) {
        sum += __shfl_down(sum, m, 64);
        cnt += __shfl_down(cnt, m, 64);
    }
    __shared__ float rs[4], rc[4];
    if ((t & 63) == 0) { rs[t >> 6] = sum; rc[t >> 6] = cnt; }
    __syncthreads();
    if (t == 0) {
        out[0] = (rs[0] + rs[1] + rs[2] + rs[3]) / (float)NPAIR;
        out[1] = (rc[0] + rc[1] + rc[2] + rc[3]) / (float)NPAIR;
    }
}

extern "C" void kernel_launch(void* const* d_in, const int* in_sizes, int n_in,
                              void* d_out, int out_size, void* d_ws, size_t ws_size,
                              hipStream_t stream) {
    const float* inputs = (const float*)d_in[0];
    float* out = (float*)d_out;
    char* ws = (char*)d_ws;
    uint8_t* f8m = (uint8_t*)ws;                               // 8 MiB
    float* sq = (float*)(ws + (size_t)N_ROWS * DIM);           // 16 KiB
    unsigned* neg_bits = (unsigned*)((char*)sq + N_ROWS * 4);  // 16 KiB
    float* dist_ap = (float*)((char*)neg_bits + N_ROWS * 4);   // 24 KiB

    prep_kernel<<<N_ROWS, 256, 0, stream>>>(inputs, f8m, sq, neg_bits);
    gemm_kernel<<<NBLK, 256, 32768, stream>>>(f8m, sq, neg_bits, dist_ap);
    finalize_kernel<<<1, 256, 0, stream>>>(neg_bits, dist_ap, out);
}

// Round 25
// 62.918 us; speedup vs baseline: 1.3029x; 1.0005x over previous
//
#include <hip/hip_runtime.h>
#include <hip/hip_bf16.h>
#include <hip/hip_fp8.h>
#include <stdint.h>

// TripletLoss (n=4096, d=2048, K=4) — fused fp8-MFMA distance + mining.
//   1. prep (R25: wave-per-row, no LDS/syncthreads): fp32 -> fp8 e4m3 via HW
//      v_cvt_pk_fp8_f32; 64B-row-tile permuted layout pos(k8) = (k8>>3)*64 +
//      (k8&3)*16 + ((k8>>2)&1)*8 (k8 = k/8). Lane reads 32 contiguous floats
//      (2 consecutive float4 per j-step, coalesced), in-wave shfl reduce for
//      sq[] (fp32-exact). Common k-perm of A@A^T is invariant.
//   2. gemm: R20/R24 proven best, byte-identical (128x128 tiles, 528 blocks,
//      4 waves x 64x64, BK=64, 32 KiB LDS, 8-phase 2-barrier skeleton,
//      VMW(2) at ph4/ph8, aligned-quad swizzle = 0 conflicts, 0.25
//      ds_read/MFMA, MFMA 16x16x32_fp8_fp8, s_setprio, XCD swizzle 528=8x66).
//      R21/R22/R23 structural variants all regressed — validated optimum.
//   3. finalize: separate 1-block kernel (R14: device-fence fusion costs 86us).

#define N_ROWS 4096
#define DIM    2048
#define P_IDS  1024
#define NPAIR  (P_IDS * 6)
#define MARGIN 0.3f
#define BK     64           // fp8 k (= bytes) per K-tile row
#define NT     (DIM / BK)   // 32 K-tiles
#define NIT    (NT / 2)     // 16 iterations (2 K-tiles each)
#define NTILE  32           // 4096 / 128
#define NBLK   528          // 32*33/2 = 8 * 66

typedef __attribute__((ext_vector_type(4))) float f32x4;
typedef __attribute__((ext_vector_type(2))) long long2v;

__global__ __launch_bounds__(256) void prep_kernel(const float* __restrict__ in,
                                                   uint8_t* __restrict__ f8m,
                                                   float* __restrict__ sq,
                                                   unsigned* __restrict__ neg_bits) {
    // One wave per row: block handles rows 4*bid .. 4*bid+3.
    const int lane = threadIdx.x & 63;
    const int row = blockIdx.x * 4 + (threadIdx.x >> 6);
    const float4* rp = (const float4*)(in + (size_t)row * DIM);
    uint8_t* orow = f8m + (size_t)row * DIM;
    float s = 0.f;
    #pragma unroll
    for (int j = 0; j < 4; ++j) {
        const int base = j * 64 + lane;        // k8 group id (8 floats)
        float4 v0 = rp[2 * base];
        float4 v1 = rp[2 * base + 1];
        s += v0.x * v0.x + v0.y * v0.y + v0.z * v0.z + v0.w * v0.w
           + v1.x * v1.x + v1.y * v1.y + v1.z * v1.z + v1.w * v1.w;
        unsigned w0 = (unsigned)__builtin_amdgcn_cvt_pk_fp8_f32(v0.x, v0.y, 0, false);
        w0 = (unsigned)__builtin_amdgcn_cvt_pk_fp8_f32(v0.z, v0.w, (int)w0, true);
        unsigned w1 = (unsigned)__builtin_amdgcn_cvt_pk_fp8_f32(v1.x, v1.y, 0, false);
        w1 = (unsigned)__builtin_amdgcn_cvt_pk_fp8_f32(v1.z, v1.w, (int)w1, true);
        // 64B-row-tile layout: k8 -> pos = (k8>>3)*64 + (k8&3)*16 + ((k8>>2)&1)*8
        const int pos = (base >> 3) * 64 + (base & 3) * 16 + ((base >> 2) & 1) * 8;
        uint2 o; o.x = w0; o.y = w1;
        *(uint2*)(orow + pos) = o;
    }
    #pragma unroll
    for (int m = 32; m; m >>= 1) s += __shfl_down(s, m, 64);
    if (lane == 0) {
        sq[row] = s;
        neg_bits[row] = 0x7F800000u;  // +inf
    }
}

__global__ __launch_bounds__(256, 4) void gemm_kernel(const uint8_t* __restrict__ f8m,
                                                      const float* __restrict__ sq,
                                                      unsigned* __restrict__ neg_bits,
                                                      float* __restrict__ dist_ap) {
    extern __shared__ char smem[];              // 32 KiB dynamic LDS
    uint8_t* const Asb = (uint8_t*)smem;        // [2][128][64] B (16 KiB)
    uint8_t* const Bsb = (uint8_t*)(smem + 16384);
    #define AS(B,R,C) Asb[((B) << 13) + ((R) << 6) + (C)]
    #define BS(B,R,C) Bsb[((B) << 13) + ((R) << 6) + (C)]

    // Bijective XCD-chunk swizzle (528 = 8 * 66).
    const int bid = (blockIdx.x & 7) * (NBLK / 8) + (blockIdx.x >> 3);
    int rem = bid, bi = 0;
    while (rem >= NTILE - bi) { rem -= NTILE - bi; ++bi; }
    const int bj = bi + rem;   // bi <= bj

    const int t = threadIdx.x;
    const int lane = t & 63;
    const int wave = t >> 6;             // 0..3
    const int wr = (wave >> 1) * 64;     // M-half (2 waves)
    const int wc = (wave & 1) * 64;      // N-half (2 waves)
    const int lr = lane & 15;
    const int l4 = lane >> 4;            // 0..3 = fragment k-quarter
    f32x4 acc[4][4] = {};

    const int rowA0 = bi * 128;
    const int rowB0 = bj * 128;
    // Staging: chunk = 16 rows x 64B = 1KB. Stage-lane s -> LDS offset s*16
    // (row s>>2, slot s&3); stored granule gg = (s&3)^((s>>3)&3) (involution
    // with the read-side XOR mask (row>>1)&3).
    const int sr  = lane >> 2;                       // 0..15 row in chunk
    const int gg  = (lane & 3) ^ ((lane >> 3) & 3);  // source granule
    const uint8_t* gA = f8m + (size_t)(rowA0 + sr) * DIM + (gg << 4);
    const uint8_t* gB = f8m + (size_t)(rowB0 + sr) * DIM + (gg << 4);

    // Stage one full 128-row K-tile (8 KiB, 8 chunks): 2 gloads/wave.
    #define STAGE_HT(GBASE, LDSB, BUF, KT)                                        \
        { _Pragma("unroll")                                                       \
          for (int g = 0; g < 2; ++g) {                                           \
              const int chunk = wave * 2 + g;                                     \
              __builtin_amdgcn_global_load_lds(                                   \
                  (const __attribute__((address_space(1))) void*)                 \
                      ((GBASE) + (size_t)chunk * 16 * DIM + (KT) * BK),           \
                  (__attribute__((address_space(3))) void*)                       \
                      ((char*)(LDSB) + (BUF) * 8192 + chunk * 1024),              \
                  16, 0, 0);                                                      \
          } }
    #define STAGE_A(BUF, KT) STAGE_HT(gA, Asb, BUF, KT)
    #define STAGE_B(BUF, KT) STAGE_HT(gB, Bsb, BUF, KT)

    // Fragment read: ONE ds_read_b128 per fragment per K-tile (halves =
    // MFMA steps ks=0,1; static component index). Slot = l4 ^ ((lr>>1)&3):
    // per-16-lane group covers 8 bank-quads x 2 lanes = conflict-free.
    long2v afp[2], bfp0[2], bfp1[2];
    #define SLOTCOL ((l4 ^ ((lr >> 1) & 3)) << 4)
    #define LOAD_AF(BUF, MH)                                                      \
        { _Pragma("unroll") for (int m = 0; m < 2; ++m)                           \
              afp[m] = *(const long2v*)&AS(BUF,                                   \
                  wr + ((MH) * 2 + m) * 16 + lr, SLOTCOL); }
    #define LOAD_BF(DST, BUF, NH)                                                 \
        { _Pragma("unroll") for (int n = 0; n < 2; ++n)                           \
              DST[n] = *(const long2v*)&BS(BUF, wc + ((NH) * 2 + n) * 16 + lr,    \
                                           SLOTCOL); }

    // 8 MFMA per quadrant burst (2m x 2n x 2ks); ks outer -> reuse dist 4.
    #define MFMA_Q(MH, NH, BF)                                                    \
        { __builtin_amdgcn_s_setprio(1);                                          \
          _Pragma("unroll") for (int ks = 0; ks < 2; ++ks)                        \
          _Pragma("unroll") for (int m = 0; m < 2; ++m)                           \
          _Pragma("unroll") for (int n = 0; n < 2; ++n)                           \
              acc[(MH) * 2 + m][(NH) * 2 + n] =                                   \
                  __builtin_amdgcn_mfma_f32_16x16x32_fp8_fp8(                     \
                      afp[m][ks], BF[n][ks],                                      \
                      acc[(MH) * 2 + m][(NH) * 2 + n], 0, 0, 0);                  \
          __builtin_amdgcn_s_setprio(0); }

    #define BARR() __builtin_amdgcn_s_barrier()
    #define VMW(N) asm volatile("s_waitcnt vmcnt(" #N ")" ::: "memory")

    // Prologue: A(0), B(0) -> buf0; B(1) -> buf1. (A(1) staged in ph1.)
    STAGE_A(0, 0);
    STAGE_B(0, 0);
    STAGE_B(1, 1);
    VMW(0);
    BARR();

    // Ledger (steady, gloads/wave): entering iter B(t+1)=2 out.
    // ph1 +A(t+1)=4; ph3 +B(t+2)=6; ph4 VMW(2) drains B(t+1),A(t+1);
    // ph5 +A(t+2)=4; ph7 +B(t+3)=6; ph8 VMW(2) drains B(t+2),A(t+2).
    for (int i = 0; i < NIT - 1; ++i) {
        const int t2 = 2 * i;
        // ph1
        LOAD_AF(0, 0); LOAD_BF(bfp0, 0, 0);
        STAGE_A(1, t2 + 1);
        BARR(); MFMA_Q(0, 0, bfp0); BARR();
        // ph2
        LOAD_BF(bfp1, 0, 1);
        BARR(); MFMA_Q(0, 1, bfp1); BARR();
        // ph3
        LOAD_AF(0, 1);
        STAGE_B(0, t2 + 2);
        BARR(); MFMA_Q(1, 1, bfp1); BARR();
        // ph4
        BARR(); MFMA_Q(1, 0, bfp0); VMW(2); BARR();
        // ph5
        LOAD_AF(1, 0); LOAD_BF(bfp0, 1, 0);
        STAGE_A(0, t2 + 2);
        BARR(); MFMA_Q(0, 0, bfp0); BARR();
        // ph6
        LOAD_BF(bfp1, 1, 1);
        BARR(); MFMA_Q(0, 1, bfp1); BARR();
        // ph7
        LOAD_AF(1, 1);
        STAGE_B(1, t2 + 3);
        BARR(); MFMA_Q(1, 1, bfp1); BARR();
        // ph8
        BARR(); MFMA_Q(1, 0, bfp0); VMW(2); BARR();
    }
    // Peeled last iteration (t2 = 30): no stages for tiles 32/33.
    {
        LOAD_AF(0, 0); LOAD_BF(bfp0, 0, 0);
        STAGE_A(1, NT - 1);
        BARR(); MFMA_Q(0, 0, bfp0); BARR();
        LOAD_BF(bfp1, 0, 1);
        BARR(); MFMA_Q(0, 1, bfp1); BARR();
        LOAD_AF(0, 1);
        BARR(); MFMA_Q(1, 1, bfp1); BARR();
        BARR(); MFMA_Q(1, 0, bfp0); VMW(0); BARR();
        LOAD_AF(1, 0); LOAD_BF(bfp0, 1, 0);
        BARR(); MFMA_Q(0, 0, bfp0); BARR();
        LOAD_BF(bfp1, 1, 1);
        BARR(); MFMA_Q(0, 1, bfp1); BARR();
        LOAD_AF(1, 1);
        BARR(); MFMA_Q(1, 1, bfp1); BARR();
        MFMA_Q(1, 0, bfp0);
    }

    // ---- fused epilogue (16x16 C/D layout: col=lane&15, row=l4*4+r) ----
    const bool diag = (bi == bj);
    const int l15 = lane & 15;
    float sqc[4];
    #pragma unroll
    for (int n = 0; n < 4; ++n) sqc[n] = sq[rowB0 + wc + n * 16 + l15];
    float colmin[4] = {INFINITY, INFINITY, INFINITY, INFINITY};

    #pragma unroll
    for (int m = 0; m < 4; ++m) {
        #pragma unroll
        for (int r = 0; r < 4; ++r) {
            const int grow = rowA0 + wr + m * 16 + l4 * 4 + r;
            const float sqr = sq[grow];
            float rmin = INFINITY;
            #pragma unroll
            for (int n = 0; n < 4; ++n) {
                const int gcol = rowB0 + wc + n * 16 + l15;
                const float d2 = sqr + sqc[n] - 2.0f * acc[m][n][r];
                const float d = sqrtf(fmaxf(d2, 1e-12f));
                float cand = d;
                if (diag && ((grow >> 2) == (gcol >> 2))) {
                    if (grow < gcol) {  // within-identity pair (a<b)
                        const int p = grow >> 2;
                        const int a = grow & 3, b = gcol & 3;
                        dist_ap[p * 6 + (a * (7 - a)) / 2 + (b - a - 1)] = d;
                    }
                    cand = INFINITY;  // mask positives from mining
                }
                rmin = fminf(rmin, cand);
                colmin[n] = fminf(colmin[n], cand);
            }
            rmin = fminf(rmin, __shfl_xor(rmin, 1, 64));
            rmin = fminf(rmin, __shfl_xor(rmin, 2, 64));
            rmin = fminf(rmin, __shfl_xor(rmin, 4, 64));
            rmin = fminf(rmin, __shfl_xor(rmin, 8, 64));
            if (l15 == 0) atomicMin(&neg_bits[grow], __float_as_uint(rmin));
        }
    }
    if (!diag) {  // transpose contribution (col mins over the wave's 64 rows)
        #pragma unroll
        for (int n = 0; n < 4; ++n) {
            float v = colmin[n];
            v = fminf(v, __shfl_xor(v, 16, 64));
            v = fminf(v, __shfl_xor(v, 32, 64));
            if (l4 == 0)
                atomicMin(&neg_bits[rowB0 + wc + n * 16 + l15], __float_as_uint(v));
        }
    }
}

__global__ __launch_bounds__(256) void finalize_kernel(const unsigned* __restrict__ neg_bits,
                                                       const float* __restrict__ dist_ap,
                                                       float* __restrict__ out) {
    const int t = threadIdx.x;
    float sum = 0.f, cnt = 0.f;
    for (int e = t; e < NPAIR; e += 256) {
        const int p = e / 6;
        const int idx = e - p * 6;
        const int a = (idx < 3) ? 0 : ((idx < 5) ? 1 : 2);  // triu jj for K=4
        const float an = __uint_as_float(neg_bits[p * 4 + a]);
        const float ap = dist_ap[e];
        sum += fmaxf(ap - an + MARGIN, 0.f);
        cnt += (an > ap) ? 1.f : 0.f;
    }
    #pragma unroll
    for (int m = 32; m; m >>= 1) {
        sum += __shfl_down(sum, m, 64);
        cnt += __shfl_down(cnt, m, 64);
    }
    __shared__ float rs[4], rc[4];
    if ((t & 63) == 0) { rs[t >> 6] = sum; rc[t >> 6] = cnt; }
    __syncthreads();
    if (t == 0) {
        out[0] = (rs[0] + rs[1] + rs[2] + rs[3]) / (float)NPAIR;
        out[1] = (rc[0] + rc[1] + rc[2] + rc[3]) / (float)NPAIR;
    }
}

extern "C" void kernel_launch(void* const* d_in, const int* in_sizes, int n_in,
                              void* d_out, int out_size, void* d_ws, size_t ws_size,
                              hipStream_t stream) {
    const float* inputs = (const float*)d_in[0];
    float* out = (float*)d_out;
    char* ws = (char*)d_ws;
    uint8_t* f8m = (uint8_t*)ws;                               // 8 MiB
    float* sq = (float*)(ws + (size_t)N_ROWS * DIM);           // 16 KiB
    unsigned* neg_bits = (unsigned*)((char*)sq + N_ROWS * 4);  // 16 KiB
    float* dist_ap = (float*)((char*)neg_bits + N_ROWS * 4);   // 24 KiB

    prep_kernel<<<N_ROWS / 4, 256, 0, stream>>>(inputs, f8m, sq, neg_bits);
    gemm_kernel<<<NBLK, 256, 32768, stream>>>(f8m, sq, neg_bits, dist_ap);
    finalize_kernel<<<1, 256, 0, stream>>>(neg_bits, dist_ap, out);
}